// Round 17
// baseline (302.084 us; speedup 1.0000x reference)
//
#include <hip/hip_runtime.h>
#include <math.h>

#define B_   16
#define V_   16
#define C_   64
#define M_   32
#define CM_  16
#define D_   128
#define OUT_ 600
#define NSEQ 256      // B*V
#define NROW 8192     // B*V*M

typedef __attribute__((ext_vector_type(8))) short bf16x8;
typedef __attribute__((ext_vector_type(4))) short bf16x4;
typedef __attribute__((ext_vector_type(2))) short bf16x2;
typedef __attribute__((ext_vector_type(4))) float f32x4;

__device__ __forceinline__ unsigned short f2bf(float x) {
  union { float f; unsigned u; } v; v.f = x;
  unsigned r = v.u + 0x7fff + ((v.u >> 16) & 1);   // RNE
  return (unsigned short)(r >> 16);
}
__device__ __forceinline__ float bf2f(short s) {
  union { unsigned u; float f; } v;
  v.u = ((unsigned)(unsigned short)s) << 16;
  return v.f;
}
// fast sigmoid / tanh: native v_exp + v_rcp (~5 inst), saturate correctly
__device__ __forceinline__ float fsig(float x)  { return __fdividef(1.f, 1.f + __expf(-x)); }
__device__ __forceinline__ float ftanh(float x) { return 1.f - 2.f*__fdividef(1.f, __expf(2.f*x) + 1.f); }

// ---- workspace layout (float units; bf16 arrays are short* views) ----
constexpr int OFF_VIS   = 0;                               // fp32 [3][256][128]
constexpr int OFF_VISB  = 98304;                           // bf16 [3][256][128]
constexpr int OFF_MONB  = 147456;                          // bf16 [2][8192][128]
constexpr int OFF_TOTB  = 1196032;                         // bf16 [2][8192][128]
constexpr int OFF_W12T  = 2244608;                         // bf16 [8][128n][256k]
constexpr int OFF_WIHB  = 2375680;                         // bf16 [5][384n][128k]
constexpr int OFF_WIHTV = 2498560;                         // fp32 [4][128][384]
constexpr int OFF_XE    = 2695168;                         // fp32 [2][256][128]
constexpr int OFF_GI    = 2760704;                         // bf16 gi3[8][64][32][384][4]
constexpr int OFF_LAST  = 27926528;                        // fp32 [8][256][128]
constexpr int OFF_VH    = 29171712;                        // fp32 [10][16][128]

// =====================================================================
// prep+vis merged — verified round 16, unchanged.
// =====================================================================
__global__ __launch_bounds__(256) void k_prepvis(
    const float* __restrict__ Wself, const float* __restrict__ Wmsg,
    const float* __restrict__ mWih,  const float* __restrict__ vWih,
    const float* __restrict__ wgt,   const float* __restrict__ age,
    const float* __restrict__ fwW,   const float* __restrict__ fwB,
    const float* __restrict__ faW,   const float* __restrict__ faB,
    const int* __restrict__ cc, const int* __restrict__ cp, const int* __restrict__ cd,
    const float* __restrict__ ec, const float* __restrict__ ep, const float* __restrict__ ed,
    short* __restrict__ w12t, short* __restrict__ wihb,
    float* __restrict__ wihTv, float* __restrict__ xe,
    float* __restrict__ vis, short* __restrict__ visb)
{
  int bx = blockIdx.x, tid = threadIdx.x;
  if (bx < 1024) {                      // w12t[pt][n][k] = bf16 combined
    int lin = bx*256 + tid;             // < 262144
    int pt = lin >> 15, rem = lin & 32767;
    int n = rem >> 8, k = rem & 255;
    float v;
    if (k < 128) v = Wself[pt*16384 + k*128 + n] - Wmsg[pt*16384 + k*128 + n]*(1.f/3.f);
    else         v = Wmsg[pt*16384 + (k-128)*128 + n]*(1.f/3.f);
    w12t[lin] = (short)f2bf(v);
  } else if (bx < 1984) {               // wihb = bf16(mWih) elementwise
    int lin = (bx-1024)*256 + tid;      // < 245760
    wihb[lin] = (short)f2bf(mWih[lin]);
  } else if (bx < 2752) {               // vgru Wih transpose fp32
    int lin = (bx-1984)*256 + tid;      // < 196608
    int g = lin / 49152, rem2 = lin % 49152;
    int k = rem2 / 384, j = rem2 % 384;
    wihTv[lin] = vWih[g*49152 + j*128 + k];
  } else if (bx < 3008) {               // xe for weight / age
    int lin = (bx-2752)*256 + tid;      // < 65536
    int which = lin >> 15, rem2 = lin & 32767;
    int n = rem2 >> 7, d = rem2 & 127;
    float x  = which ? age[n] : wgt[n];
    float Wv = which ? faW[d] : fwW[d];
    float bb = which ? faB[d] : fwB[d];
    xe[lin] = (x != 0.0f) ? (x*Wv + bb) : 0.0f;
  } else {                              // visit-event sum pools
    int idx = (bx-3008)*256 + tid;      // < 98304
    int type = idx >> 15;
    int r = idx & 32767;
    int bv = r >> 7, d = r & 127;
    const int*   codes = (type==0) ? cc : (type==1) ? cp : cd;
    const float* emb   = (type==0) ? ec : (type==1) ? ep : ed;
    float acc = 0.f;
    for (int c = 0; c < C_; ++c) {
      int code = codes[bv*C_ + c];
      acc += emb[code*D_ + d];
    }
    vis [(type*NSEQ + bv)*D_ + d] = acc;
    visb[(type*NSEQ + bv)*D_ + d] = (short)f2bf(acc);
  }
}

// =====================================================================
// monitor-event pools — unchanged (verified).
// =====================================================================
__global__ __launch_bounds__(128) void k_mon(
    const int* __restrict__ cli, const int* __restrict__ clv,
    const int* __restrict__ cii, const int* __restrict__ civ,
    const float* __restrict__ eli, const float* __restrict__ elv,
    const float* __restrict__ eii, const float* __restrict__ eiv,
    const float* __restrict__ vis,
    short* __restrict__ monb, short* __restrict__ totb)
{
  int p   = blockIdx.x >> 13;
  int bvm = blockIdx.x & 8191;
  int d   = threadIdx.x;
  const int* ci = p ? cii : cli;  const int* cv = p ? civ : clv;
  const float* ei = p ? eii : eli; const float* ev = p ? eiv : elv;
  float acc = 0.f;
  #pragma unroll
  for (int c = 0; c < CM_; ++c) {
    int iv = ci[bvm*CM_ + c];
    int vv = cv[bvm*CM_ + c];
    acc += ei[iv*D_ + d] * ev[vv*D_ + d];
  }
  int bv = bvm >> 5;
  float vsum = vis[bv*D_ + d] + vis[(NSEQ + bv)*D_ + d] + vis[(2*NSEQ + bv)*D_ + d];
  monb[(p*NROW + bvm)*D_ + d] = (short)f2bf(acc);
  totb[(p*NROW + bvm)*D_ + d] = (short)f2bf(acc + vsum);
}

// =====================================================================
// FUSED GNN+GI v3 (MFMA bf16): row tile 128 -> 64, grid 1024 = 4 blk/CU.
// Per-block work halved (stage1 64 MFMA/wave, stage2 96); cross-block
// overlap fills barrier bubbles. gi3 layout unchanged; a block writes the
// 8B s4-half {half*2, half*2+1} of each 16B group — sibling halves are
// blocks bx and bx+512 (512 % 8 == 0 -> SAME XCD, L2 merges the line;
// avoids round-9's cross-XCD false sharing). mgru reads unchanged.
// =====================================================================
__global__ __launch_bounds__(256, 4) void k_gg(
    const short* __restrict__ monb, const short* __restrict__ totb,
    const short* __restrict__ visb, const short* __restrict__ w12t,
    const short* __restrict__ wihb, const float* __restrict__ mbih,
    short* __restrict__ gi)
{
  const int bx = blockIdx.x;
  const int half = bx >> 9;                // 0/1; siblings bx, bx+512 same XCD
  const int pt = (bx & 511) >> 6;          // run 0..7
  const int rb = bx & 63;
  const int p = pt >> 2, t = pt & 3;
  const int g = (pt % 4 == 0) ? (pt / 4) : (pt % 4 + 1);
  const int row0 = rb * 128 + half * 64;   // 64 rows
  const int tid = threadIdx.x;
  const int w = tid >> 6, lane = tid & 63;
  const int c = lane & 15, q = lane >> 4;

  __shared__ short smem[64*72 + 128*72];   // 27648 B
  short (*Xs)[72]  = (short(*)[72])smem;            // 64 x 72
  short (*Ws)[72]  = (short(*)[72])(smem + 64*72);  // 128 x 72
  short (*Ys)[136] = (short(*)[136])smem;           // 64 x 136 (aliases)
  float (*giS)[68] = (float(*)[68])smem;            // 64 x 68 fp32 (aliases)

  const int rowL = tid >> 2;               // 0..63
  const int kq   = tid & 3;                // 16-k chunk for X staging
  const int rowG = row0 + rowL;
  const int bv   = rowG >> 5;

  f32x4 acc1[8];
  #pragma unroll
  for (int ni = 0; ni < 8; ++ni) acc1[ni] = (f32x4){0.f,0.f,0.f,0.f};

  const short* featp = (t == 0) ? (monb + ((size_t)p*NROW + rowG)*128)
                                : (visb + ((size_t)(t-1)*NSEQ + bv)*128);
  const short* totp  = totb + ((size_t)p*NROW + rowG)*128;
  const short* wrow  = w12t + ((size_t)pt*128 + (tid>>1))*256;

  #pragma unroll 1
  for (int ks = 0; ks < 4; ++ks) {
    __syncthreads();
    // X: 64 rows x 64 k (16 k per thread)
    int kg = ks*64 + kq*16;
    const short* srcX = (kg < 128) ? (featp + kg) : (totp + (kg - 128));
    *(bf16x8*)&Xs[rowL][kq*16]     = *(const bf16x8*)(srcX);
    *(bf16x8*)&Xs[rowL][kq*16 + 8] = *(const bf16x8*)(srcX + 8);
    // W: 128 n x 64 k (32 k per thread)
    const short* srcW = wrow + ks*64 + (tid&1)*32;
    short* dW = &Ws[tid>>1][(tid&1)*32];
    #pragma unroll
    for (int i = 0; i < 4; ++i)
      *(bf16x8*)(dW + 8*i) = *(const bf16x8*)(srcW + 8*i);
    __syncthreads();
    #pragma unroll
    for (int kk = 0; kk < 2; ++kk) {
      bf16x8 af = *(const bf16x8*)&Xs[w*16 + c][kk*32 + q*8];
      #pragma unroll
      for (int ni = 0; ni < 8; ++ni) {
        bf16x8 bfr = *(const bf16x8*)&Ws[ni*16 + c][kk*32 + q*8];
        acc1[ni] = __builtin_amdgcn_mfma_f32_16x16x32_bf16(af, bfr, acc1[ni], 0, 0, 0);
      }
    }
  }
  __syncthreads();     // done reading Xs/Ws (Ys aliases them)

  // relu + C-layout (col=lane&15, row=(lane>>4)*4+reg) -> Ys[row][col] bf16
  #pragma unroll
  for (int ni = 0; ni < 8; ++ni)
    #pragma unroll
    for (int reg = 0; reg < 4; ++reg)
      Ys[w*16 + q*4 + reg][ni*16 + c] = (short)f2bf(fmaxf(acc1[ni][reg], 0.f));
  __syncthreads();

  // ---- stage 2: gi = Y @ Wih^T + bih ----
  bf16x8 Af[4];
  #pragma unroll
  for (int kt = 0; kt < 4; ++kt)
    Af[kt] = *(const bf16x8*)&Ys[w*16 + c][kt*32 + q*8];

  float bihv[24];
  #pragma unroll
  for (int nt = 0; nt < 24; ++nt)
    bihv[nt] = mbih[g*384 + nt*16 + c];

  short* gslab = gi + (((size_t)pt*64 + rb)*32)*384*4 + half*2;
  #pragma unroll 1
  for (int cn = 0; cn < 6; ++cn) {
    f32x4 acc2[4];
    #pragma unroll
    for (int ni = 0; ni < 4; ++ni) acc2[ni] = (f32x4){0.f,0.f,0.f,0.f};
    #pragma unroll
    for (int ni = 0; ni < 4; ++ni) {
      int n = (cn*4 + ni)*16 + c;
      const short* bp_ = wihb + ((size_t)g*384 + n)*128 + q*8;
      #pragma unroll
      for (int kt = 0; kt < 4; ++kt) {
        bf16x8 bfr = *(const bf16x8*)(bp_ + kt*32);
        acc2[ni] = __builtin_amdgcn_mfma_f32_16x16x32_bf16(Af[kt], bfr, acc2[ni], 0, 0, 0);
      }
    }
    __syncthreads();   // previous chunk's giS fully consumed (Af/Ys safe in regs)
    #pragma unroll
    for (int ni = 0; ni < 4; ++ni) {
      float bia = bihv[cn*4+ni];
      #pragma unroll
      for (int reg = 0; reg < 4; ++reg)
        giS[w*16 + q*4 + reg][ni*16 + c] = acc2[ni][reg] + bia;
    }
    __syncthreads();
    // store: local row r = seqL*32 + m ; s4 = half*2 + seqL ; bf16x2 per (m,colL)
    #pragma unroll
    for (int k2 = 0; k2 < 8; ++k2) {
      int o = tid + k2*256;            // 0..2047
      int m = o >> 6, colL = o & 63;
      bf16x2 v;
      v[0] = (short)f2bf(giS[m][colL]);        // seqL 0
      v[1] = (short)f2bf(giS[32+m][colL]);     // seqL 1
      *(bf16x2*)&gslab[((size_t)m*384 + cn*64 + colL)*4] = v;
    }
  }
}

// =====================================================================
// monitor-level GRU v6.2 (MFMA) — verified round 13/15/16, unchanged.
// =====================================================================
__global__ __launch_bounds__(512, 1) void k_mgru(
    const short* __restrict__ gi, const float* __restrict__ mWhh,
    const float* __restrict__ mbhh, float* __restrict__ last)
{
  const int run = blockIdx.x >> 5, grp = blockIdx.x & 31;
  const int g = (run % 4 == 0) ? (run / 4) : (run % 4 + 1);
  const int tid = threadIdx.x;
  const int w = tid >> 6;            // wave 0..7
  const int lane = tid & 63;
  const int c = lane & 15, q = lane >> 4;

  __shared__ short hb[2][4][16][40];
  for (int idx = tid; idx < 2*4*16*40; idx += 512)
    ((short*)hb)[idx] = 0;

  const int jh = w*16 + c;           // hidden index 0..127 (wave-sliced)

  bf16x8 bfrag[3][4];
  #pragma unroll
  for (int gate = 0; gate < 3; ++gate) {
    const float* wp = mWhh + ((size_t)g*384 + gate*128 + jh)*128 + q*8;
    #pragma unroll
    for (int kt = 0; kt < 4; ++kt) {
      float4 lo = *(const float4*)(wp + kt*32);
      float4 hi = *(const float4*)(wp + kt*32 + 4);
      bf16x8 t;
      t[0]=(short)f2bf(lo.x); t[1]=(short)f2bf(lo.y); t[2]=(short)f2bf(lo.z); t[3]=(short)f2bf(lo.w);
      t[4]=(short)f2bf(hi.x); t[5]=(short)f2bf(hi.y); t[6]=(short)f2bf(hi.z); t[7]=(short)f2bf(hi.w);
      bfrag[gate][kt] = t;
    }
  }
  float bh_[3];
  #pragma unroll
  for (int gate = 0; gate < 3; ++gate)
    bh_[gate] = mbhh[g*384 + gate*128 + jh];

  float hf[4] = {0.f,0.f,0.f,0.f};
  const short* gib = gi + (((size_t)run*64 + grp*2 + q)*32)*384*4;  // bf16 [m][384][4]
  const bool act = (lane < 32);

  bf16x4 gA[3], gB[3];
  if (act) {
    #pragma unroll
    for (int gate = 0; gate < 3; ++gate)
      gA[gate] = *(const bf16x4*)&gib[(size_t)(0*384 + gate*128 + jh)*4];
  }
  __syncthreads();

  auto dostep = [&](int m, bf16x4 (&gcur)[3], bf16x4 (&gnext)[3]) {
    const int cur = m & 1, nxt = cur ^ 1;
    bf16x8 a[4];
    #pragma unroll
    for (int kt = 0; kt < 4; ++kt)
      a[kt] = *(const bf16x8*)&hb[cur][kt][c][q*8];

    f32x4 acc[3];
    #pragma unroll
    for (int gate = 0; gate < 3; ++gate) {
      f32x4 t = {0.f,0.f,0.f,0.f};
      #pragma unroll
      for (int kt = 0; kt < 4; ++kt)
        t = __builtin_amdgcn_mfma_f32_16x16x32_bf16(a[kt], bfrag[gate][kt], t, 0, 0, 0);
      acc[gate] = t;
    }

    if (act && m < 31) {
      #pragma unroll
      for (int gate = 0; gate < 3; ++gate)
        gnext[gate] = *(const bf16x4*)&gib[(size_t)((m+1)*384 + gate*128 + jh)*4];
    }

    if (act) {
      const int kt = jh >> 5, kk = jh & 31;
      #pragma unroll
      for (int reg = 0; reg < 4; ++reg) {
        int row = q*4 + reg;
        float g0 = bf2f(gcur[0][reg]);
        float g1 = bf2f(gcur[1][reg]);
        float g2 = bf2f(gcur[2][reg]);
        float rr = fsig(acc[0][reg] + bh_[0] + g0);
        float zz = fsig(acc[1][reg] + bh_[1] + g1);
        float nn = ftanh(g2 + rr*(acc[2][reg] + bh_[2]));
        float hnew = (1.f - zz)*nn + zz*hf[reg];
        hf[reg] = hnew;
        hb[nxt][kt][row][kk] = (short)f2bf(hnew);
      }
    }
    __syncthreads();
  };

  #pragma unroll 1
  for (int m2 = 0; m2 < 16; ++m2) {
    dostep(2*m2,     gA, gB);
    dostep(2*m2 + 1, gB, gA);
  }

  if (act) {
    #pragma unroll
    for (int reg = 0; reg < 4; ++reg)
      last[(run*NSEQ + grp*8 + q*4 + reg)*D_ + jh] = hf[reg];
  }
}

// =====================================================================
// visit-level GRU v3 (vgi fused) — verified round 16, unchanged.
// =====================================================================
__global__ __launch_bounds__(768) void k_vgru(
    const float* __restrict__ last, const float* __restrict__ xe,
    const float* __restrict__ wihTv, const float* __restrict__ vbih,
    const float* __restrict__ vWhh, const float* __restrict__ vbhh,
    float* __restrict__ vh)
{
  int run = blockIdx.x >> 4, b = blockIdx.x & 15;
  int tid = threadIdx.x;
  int vidx = (run < 4) ? 0 : (run < 8) ? 1 : (run - 6);

  __shared__ float Xs[16][128];          // 8 KB
  __shared__ float giL[16*384];          // 24 KB
  __shared__ __align__(16) float hsv[128];
  __shared__ float gh[384];

  const float* X = (run < 8) ? (last + ((size_t)run*NSEQ + b*16)*D_)
                             : (xe + ((size_t)(run-8)*NSEQ + b*16)*D_);
  for (int idx = tid; idx < 2048; idx += 768)
    ((float*)Xs)[idx] = X[idx];
  if (tid < 128) hsv[tid] = 0.f;
  __syncthreads();

  // ---- gi precompute into LDS: thread (half, j) does 8 visits ----
  {
    int half = (tid >= 384) ? 1 : 0;
    int j = tid - half*384;
    float accv[8];
    float bias = vbih[vidx*384 + j];
    #pragma unroll
    for (int s = 0; s < 8; ++s) accv[s] = bias;
    const float* W = wihTv + vidx*49152 + j;
    #pragma unroll 4
    for (int k = 0; k < 128; ++k) {
      float wv = W[k*384];
      #pragma unroll
      for (int s = 0; s < 8; ++s) accv[s] += Xs[half*8 + s][k] * wv;
    }
    #pragma unroll
    for (int s = 0; s < 8; ++s)
      giL[(half*8 + s)*384 + j] = accv[s];
  }

  // ---- recurrence weights (pair-split, w[64]/thread, no spill) ----
  int j = tid >> 1, kh = tid & 1;
  float w[64];
  const float4* wrow = (const float4*)(vWhh + (vidx*384 + j)*128 + kh*64);
  #pragma unroll
  for (int k4 = 0; k4 < 16; ++k4) {
    float4 t4 = wrow[k4];
    w[4*k4] = t4.x; w[4*k4+1] = t4.y; w[4*k4+2] = t4.z; w[4*k4+3] = t4.w;
  }
  float bj = vbhh[vidx*384 + j];
  __syncthreads();

  #pragma unroll 1
  for (int v = 0; v < 16; ++v) {
    const float4* h4 = (const float4*)(hsv + kh*64);
    float p0 = 0.f, p1 = 0.f;
    #pragma unroll
    for (int k4 = 0; k4 < 8; ++k4) {
      float4 u0 = h4[k4], u1 = h4[k4+8];
      p0 += w[4*k4   ]*u0.x + w[4*k4+1 ]*u0.y + w[4*k4+2 ]*u0.z + w[4*k4+3 ]*u0.w;
      p1 += w[4*k4+32]*u1.x + w[4*k4+33]*u1.y + w[4*k4+34]*u1.z + w[4*k4+35]*u1.w;
    }
    float part = p0 + p1;
    part += __shfl_xor(part, 1);
    if (kh == 0) gh[j] = bj + ((j < 256) ? giL[v*384 + j] : 0.f) + part;
    __syncthreads();
    if (tid < 128) {
      float r = fsig(gh[tid]);
      float z = fsig(gh[tid+128]);
      float gin = giL[v*384 + 256 + tid];
      float n = ftanh(gin + r*gh[tid+256]);
      hsv[tid] = (1.f - z)*n + z*hsv[tid];
    }
    __syncthreads();
  }
  if (tid < 128) vh[(run*16 + b)*D_ + tid] = hsv[tid];
}

// =====================================================================
// head v4 (pe fused) — verified round 16, unchanged.
// =====================================================================
__global__ __launch_bounds__(256) void k_head(
    const float* __restrict__ vh, const float* __restrict__ Wp,
    const float* __restrict__ bp, float* __restrict__ out)
{
  const int o = blockIdx.x;
  const int tid = threadIdx.x;
  const int b = tid & 15, kc = tid >> 4;
  const int a1[7] = {0,1,2,3,4,8,9};
  const int a2[7] = {-1,5,6,7,-1,-1,-1};
  const float4* wb = (const float4*)(Wp + (size_t)o*896 + kc*56);
  float acc = 0.f;
  #pragma unroll
  for (int i = 0; i < 14; ++i) {
    int cc2 = kc*56 + i*4;
    int s = cc2 >> 7, d0 = cc2 & 127;
    float4 a = *(const float4*)(vh + (a1[s]*16 + b)*D_ + d0);
    int s2 = a2[s];
    if (s2 >= 0) {
      float4 a2v = *(const float4*)(vh + (s2*16 + b)*D_ + d0);
      a.x += a2v.x; a.y += a2v.y; a.z += a2v.z; a.w += a2v.w;
    }
    a.x = fmaxf(a.x, 0.f); a.y = fmaxf(a.y, 0.f);
    a.z = fmaxf(a.z, 0.f); a.w = fmaxf(a.w, 0.f);
    float4 ww = wb[i];
    acc += a.x*ww.x + a.y*ww.y + a.z*ww.z + a.w*ww.w;
  }
  __shared__ float red[16][17];
  red[kc][b] = acc;
  __syncthreads();
  if (tid < 16) {
    float s = 0.f;
    #pragma unroll
    for (int k = 0; k < 16; ++k) s += red[k][tid];
    out[tid*OUT_ + o] = s + bp[o];
  }
}

// =====================================================================
extern "C" void kernel_launch(void* const* d_in, const int* in_sizes, int n_in,
                              void* d_out, int out_size, void* d_ws, size_t ws_size,
                              hipStream_t stream)
{
  (void)in_sizes; (void)n_in; (void)out_size; (void)ws_size;
  const int*   cc   = (const int*)  d_in[0];
  const int*   cp   = (const int*)  d_in[1];
  const int*   cd   = (const int*)  d_in[2];
  const int*   cli  = (const int*)  d_in[3];
  const int*   clv  = (const int*)  d_in[4];
  const int*   cii  = (const int*)  d_in[5];
  const int*   civ  = (const int*)  d_in[6];
  const float* wgt  = (const float*)d_in[7];
  const float* age  = (const float*)d_in[8];
  const float* ec   = (const float*)d_in[9];
  const float* ep   = (const float*)d_in[10];
  const float* ed   = (const float*)d_in[11];
  const float* eli  = (const float*)d_in[12];
  const float* elv  = (const float*)d_in[13];
  const float* eii  = (const float*)d_in[14];
  const float* eiv  = (const float*)d_in[15];
  const float* mWih = (const float*)d_in[16];
  const float* mWhh = (const float*)d_in[17];
  const float* mbih = (const float*)d_in[18];
  const float* mbhh = (const float*)d_in[19];
  const float* vWih = (const float*)d_in[20];
  const float* vWhh = (const float*)d_in[21];
  const float* vbih = (const float*)d_in[22];
  const float* vbhh = (const float*)d_in[23];
  const float* Wself= (const float*)d_in[24];
  const float* Wmsg = (const float*)d_in[25];
  const float* fwW  = (const float*)d_in[26];
  const float* fwB  = (const float*)d_in[27];
  const float* faW  = (const float*)d_in[28];
  const float* faB  = (const float*)d_in[29];
  const float* Wp   = (const float*)d_in[30];
  const float* bp   = (const float*)d_in[31];
  float* out = (float*)d_out;
  float* ws  = (float*)d_ws;

  float* vis   = ws + OFF_VIS;
  short* visb  = (short*)(ws + OFF_VISB);
  short* monb  = (short*)(ws + OFF_MONB);
  short* totb  = (short*)(ws + OFF_TOTB);
  short* w12t  = (short*)(ws + OFF_W12T);
  short* wihb  = (short*)(ws + OFF_WIHB);
  float* wihTv = ws + OFF_WIHTV;
  float* xe    = ws + OFF_XE;
  short* gi    = (short*)(ws + OFF_GI);
  float* last  = ws + OFF_LAST;
  float* vh    = ws + OFF_VH;

  k_prepvis<<<3392, 256, 0, stream>>>(Wself, Wmsg, mWih, vWih, wgt, age,
                                      fwW, fwB, faW, faB,
                                      cc, cp, cd, ec, ep, ed,
                                      w12t, wihb, wihTv, xe, vis, visb);
  k_mon <<<16384, 128, 0, stream>>>(cli, clv, cii, civ, eli, elv, eii, eiv,
                                    vis, monb, totb);
  k_gg  <<<1024, 256, 0, stream>>>(monb, totb, visb, w12t, wihb, mbih, gi);
  k_mgru<<<256, 512, 0, stream>>>(gi, mWhh, mbhh, last);
  k_vgru<<<160, 768, 0, stream>>>(last, xe, wihTv, vbih, vWhh, vbhh, vh);
  k_head<<<600, 256, 0, stream>>>(vh, Wp, bp, out);
}

// Round 18
// 275.936 us; speedup vs baseline: 1.0948x; 1.0948x over previous
//
#include <hip/hip_runtime.h>
#include <math.h>

#define B_   16
#define V_   16
#define C_   64
#define M_   32
#define CM_  16
#define D_   128
#define OUT_ 600
#define NSEQ 256      // B*V
#define NROW 8192     // B*V*M

typedef __attribute__((ext_vector_type(8))) short bf16x8;
typedef __attribute__((ext_vector_type(4))) short bf16x4;
typedef __attribute__((ext_vector_type(4))) float f32x4;

__device__ __forceinline__ unsigned short f2bf(float x) {
  union { float f; unsigned u; } v; v.f = x;
  unsigned r = v.u + 0x7fff + ((v.u >> 16) & 1);   // RNE
  return (unsigned short)(r >> 16);
}
__device__ __forceinline__ float bf2f(short s) {
  union { unsigned u; float f; } v;
  v.u = ((unsigned)(unsigned short)s) << 16;
  return v.f;
}
// fast sigmoid / tanh: native v_exp + v_rcp (~5 inst), saturate correctly
__device__ __forceinline__ float fsig(float x)  { return __fdividef(1.f, 1.f + __expf(-x)); }
__device__ __forceinline__ float ftanh(float x) { return 1.f - 2.f*__fdividef(1.f, __expf(2.f*x) + 1.f); }

// ---- workspace layout (float units; bf16 arrays are short* views) ----
constexpr int OFF_VIS   = 0;                               // fp32 [3][256][128]
constexpr int OFF_VISB  = 98304;                           // bf16 [3][256][128]
constexpr int OFF_MONB  = 147456;                          // bf16 [2][8192][128]
constexpr int OFF_TOTB  = 1196032;                         // bf16 [2][8192][128]
constexpr int OFF_W12T  = 2244608;                         // bf16 [8][128n][256k]
constexpr int OFF_WIHB  = 2375680;                         // bf16 [5][384n][128k]
constexpr int OFF_WIHTV = 2498560;                         // fp32 [4][128][384]
constexpr int OFF_XE    = 2695168;                         // fp32 [2][256][128]
constexpr int OFF_GI    = 2760704;                         // bf16 gi3[8][64][32][384][4]
constexpr int OFF_LAST  = 27926528;                        // fp32 [8][256][128]
constexpr int OFF_VH    = 29171712;                        // fp32 [10][16][128]

// =====================================================================
// prep+vis merged — verified round 16, unchanged.
// =====================================================================
__global__ __launch_bounds__(256) void k_prepvis(
    const float* __restrict__ Wself, const float* __restrict__ Wmsg,
    const float* __restrict__ mWih,  const float* __restrict__ vWih,
    const float* __restrict__ wgt,   const float* __restrict__ age,
    const float* __restrict__ fwW,   const float* __restrict__ fwB,
    const float* __restrict__ faW,   const float* __restrict__ faB,
    const int* __restrict__ cc, const int* __restrict__ cp, const int* __restrict__ cd,
    const float* __restrict__ ec, const float* __restrict__ ep, const float* __restrict__ ed,
    short* __restrict__ w12t, short* __restrict__ wihb,
    float* __restrict__ wihTv, float* __restrict__ xe,
    float* __restrict__ vis, short* __restrict__ visb)
{
  int bx = blockIdx.x, tid = threadIdx.x;
  if (bx < 1024) {                      // w12t[pt][n][k] = bf16 combined
    int lin = bx*256 + tid;             // < 262144
    int pt = lin >> 15, rem = lin & 32767;
    int n = rem >> 8, k = rem & 255;
    float v;
    if (k < 128) v = Wself[pt*16384 + k*128 + n] - Wmsg[pt*16384 + k*128 + n]*(1.f/3.f);
    else         v = Wmsg[pt*16384 + (k-128)*128 + n]*(1.f/3.f);
    w12t[lin] = (short)f2bf(v);
  } else if (bx < 1984) {               // wihb = bf16(mWih) elementwise
    int lin = (bx-1024)*256 + tid;      // < 245760
    wihb[lin] = (short)f2bf(mWih[lin]);
  } else if (bx < 2752) {               // vgru Wih transpose fp32
    int lin = (bx-1984)*256 + tid;      // < 196608
    int g = lin / 49152, rem2 = lin % 49152;
    int k = rem2 / 384, j = rem2 % 384;
    wihTv[lin] = vWih[g*49152 + j*128 + k];
  } else if (bx < 3008) {               // xe for weight / age
    int lin = (bx-2752)*256 + tid;      // < 65536
    int which = lin >> 15, rem2 = lin & 32767;
    int n = rem2 >> 7, d = rem2 & 127;
    float x  = which ? age[n] : wgt[n];
    float Wv = which ? faW[d] : fwW[d];
    float bb = which ? faB[d] : fwB[d];
    xe[lin] = (x != 0.0f) ? (x*Wv + bb) : 0.0f;
  } else {                              // visit-event sum pools
    int idx = (bx-3008)*256 + tid;      // < 98304
    int type = idx >> 15;
    int r = idx & 32767;
    int bv = r >> 7, d = r & 127;
    const int*   codes = (type==0) ? cc : (type==1) ? cp : cd;
    const float* emb   = (type==0) ? ec : (type==1) ? ep : ed;
    float acc = 0.f;
    for (int c = 0; c < C_; ++c) {
      int code = codes[bv*C_ + c];
      acc += emb[code*D_ + d];
    }
    vis [(type*NSEQ + bv)*D_ + d] = acc;
    visb[(type*NSEQ + bv)*D_ + d] = (short)f2bf(acc);
  }
}

// =====================================================================
// monitor-event pools — unchanged (verified).
// =====================================================================
__global__ __launch_bounds__(128) void k_mon(
    const int* __restrict__ cli, const int* __restrict__ clv,
    const int* __restrict__ cii, const int* __restrict__ civ,
    const float* __restrict__ eli, const float* __restrict__ elv,
    const float* __restrict__ eii, const float* __restrict__ eiv,
    const float* __restrict__ vis,
    short* __restrict__ monb, short* __restrict__ totb)
{
  int p   = blockIdx.x >> 13;
  int bvm = blockIdx.x & 8191;
  int d   = threadIdx.x;
  const int* ci = p ? cii : cli;  const int* cv = p ? civ : clv;
  const float* ei = p ? eii : eli; const float* ev = p ? eiv : elv;
  float acc = 0.f;
  #pragma unroll
  for (int c = 0; c < CM_; ++c) {
    int iv = ci[bvm*CM_ + c];
    int vv = cv[bvm*CM_ + c];
    acc += ei[iv*D_ + d] * ev[vv*D_ + d];
  }
  int bv = bvm >> 5;
  float vsum = vis[bv*D_ + d] + vis[(NSEQ + bv)*D_ + d] + vis[(2*NSEQ + bv)*D_ + d];
  monb[(p*NROW + bvm)*D_ + d] = (short)f2bf(acc);
  totb[(p*NROW + bvm)*D_ + d] = (short)f2bf(acc + vsum);
}

// =====================================================================
// FUSED GNN+GI (MFMA bf16) — REVERTED to the round-13/15/16 verified
// 128-row kernel: ONE block owns every gi3 cache line (both 64-row split
// attempts, r9 s-width-8 and r17 same-XCD 8B halves, doubled WRITE_SIZE
// via partial-line writebacks). bf16 gi in gi3[pt][rb][m][384][4].
// =====================================================================
__global__ __launch_bounds__(256, 4) void k_gg(
    const short* __restrict__ monb, const short* __restrict__ totb,
    const short* __restrict__ visb, const short* __restrict__ w12t,
    const short* __restrict__ wihb, const float* __restrict__ mbih,
    short* __restrict__ gi)
{
  const int pt = blockIdx.x >> 6;          // run 0..7
  const int rb = blockIdx.x & 63;
  const int p = pt >> 2, t = pt & 3;
  const int g = (pt % 4 == 0) ? (pt / 4) : (pt % 4 + 1);
  const int row0 = rb * 128;
  const int tid = threadIdx.x;
  const int w = tid >> 6, lane = tid & 63;
  const int c = lane & 15, q = lane >> 4;

  __shared__ short smem[2*128*72];         // 36864 B; Ys / giS alias
  short (*Xs)[72]  = (short(*)[72])smem;
  short (*Ws)[72]  = (short(*)[72])(smem + 128*72);
  short (*Ys)[136] = (short(*)[136])smem;
  float (*giS)[68] = (float(*)[68])smem;   // 128 x 68 fp32 = 34816 B

  const int rowL = tid >> 1, kc = tid & 1;
  const int rowG = row0 + rowL;
  const int bv = rowG >> 5;
  const int mg = w >> 1, ng = w & 1;

  f32x4 acc1[4][4];
  #pragma unroll
  for (int mi = 0; mi < 4; ++mi)
    #pragma unroll
    for (int ni = 0; ni < 4; ++ni) acc1[mi][ni] = (f32x4){0.f,0.f,0.f,0.f};

  const short* featp = (t == 0) ? (monb + ((size_t)p*NROW + rowG)*128)
                                : (visb + ((size_t)(t-1)*NSEQ + bv)*128);
  const short* totp  = totb + ((size_t)p*NROW + rowG)*128;
  const short* wrow  = w12t + ((size_t)pt*128 + rowL)*256;

  #pragma unroll 1
  for (int ks = 0; ks < 4; ++ks) {
    __syncthreads();
    int kg = ks*64 + kc*32;
    const short* srcX = (kg < 128) ? (featp + kg) : (totp + (kg - 128));
    const short* srcW = wrow + kg;
    short* dX = &Xs[rowL][kc*32];
    short* dW = &Ws[rowL][kc*32];
    #pragma unroll
    for (int i = 0; i < 4; ++i) {
      *(bf16x8*)(dX + 8*i) = *(const bf16x8*)(srcX + 8*i);
      *(bf16x8*)(dW + 8*i) = *(const bf16x8*)(srcW + 8*i);
    }
    __syncthreads();
    #pragma unroll
    for (int kk = 0; kk < 2; ++kk) {
      bf16x8 af[4], bfr[4];
      #pragma unroll
      for (int mi = 0; mi < 4; ++mi)
        af[mi] = *(const bf16x8*)&Xs[(mg*4+mi)*16 + c][kk*32 + q*8];
      #pragma unroll
      for (int ni = 0; ni < 4; ++ni)
        bfr[ni] = *(const bf16x8*)&Ws[(ng*4+ni)*16 + c][kk*32 + q*8];
      #pragma unroll
      for (int mi = 0; mi < 4; ++mi)
        #pragma unroll
        for (int ni = 0; ni < 4; ++ni)
          acc1[mi][ni] = __builtin_amdgcn_mfma_f32_16x16x32_bf16(af[mi], bfr[ni], acc1[mi][ni], 0, 0, 0);
    }
  }
  __syncthreads();     // done reading Xs/Ws (Ys aliases them)

  // relu + C-layout (col=lane&15, row=(lane>>4)*4+reg) -> Ys[row][col] bf16
  #pragma unroll
  for (int mi = 0; mi < 4; ++mi)
    #pragma unroll
    for (int ni = 0; ni < 4; ++ni)
      #pragma unroll
      for (int reg = 0; reg < 4; ++reg)
        Ys[(mg*4+mi)*16 + q*4 + reg][(ng*4+ni)*16 + c] =
            (short)f2bf(fmaxf(acc1[mi][ni][reg], 0.f));
  __syncthreads();

  // ---- stage 2: gi = Y @ Wih^T + bih ----
  bf16x8 Af[2][4];
  #pragma unroll
  for (int mi = 0; mi < 2; ++mi)
    #pragma unroll
    for (int kt = 0; kt < 4; ++kt)
      Af[mi][kt] = *(const bf16x8*)&Ys[(w*2+mi)*16 + c][kt*32 + q*8];

  float bihv[24];
  #pragma unroll
  for (int nt = 0; nt < 24; ++nt)
    bihv[nt] = mbih[g*384 + nt*16 + c];

  short* gslab = gi + (((size_t)pt*64 + rb)*32)*384*4;   // bf16 [m][col][s4]
  #pragma unroll 1
  for (int cn = 0; cn < 6; ++cn) {
    f32x4 acc2[2][4];
    #pragma unroll
    for (int mi = 0; mi < 2; ++mi)
      #pragma unroll
      for (int ni = 0; ni < 4; ++ni) acc2[mi][ni] = (f32x4){0.f,0.f,0.f,0.f};
    #pragma unroll
    for (int ni = 0; ni < 4; ++ni) {
      int n = (cn*4 + ni)*16 + c;
      const short* bp_ = wihb + ((size_t)g*384 + n)*128 + q*8;
      #pragma unroll
      for (int kt = 0; kt < 4; ++kt) {
        bf16x8 bfr = *(const bf16x8*)(bp_ + kt*32);
        #pragma unroll
        for (int mi = 0; mi < 2; ++mi)
          acc2[mi][ni] = __builtin_amdgcn_mfma_f32_16x16x32_bf16(Af[mi][kt], bfr, acc2[mi][ni], 0, 0, 0);
      }
    }
    __syncthreads();
    #pragma unroll
    for (int mi = 0; mi < 2; ++mi)
      #pragma unroll
      for (int ni = 0; ni < 4; ++ni) {
        float bia = bihv[cn*4+ni];
        #pragma unroll
        for (int reg = 0; reg < 4; ++reg)
          giS[(w*2+mi)*16 + q*4 + reg][ni*16 + c] = acc2[mi][ni][reg] + bia;
      }
    __syncthreads();
    #pragma unroll
    for (int k = 0; k < 8; ++k) {
      int o4 = tid + k*256;            // 0..2047
      int m = o4 >> 6, colL = o4 & 63;
      bf16x4 v;
      v[0] = (short)f2bf(giS[m][colL]);
      v[1] = (short)f2bf(giS[32+m][colL]);
      v[2] = (short)f2bf(giS[64+m][colL]);
      v[3] = (short)f2bf(giS[96+m][colL]);
      *(bf16x4*)&gslab[((size_t)m*384 + cn*64 + colL)*4] = v;
    }
  }
}

// =====================================================================
// monitor-level GRU v6.2 (MFMA) — verified round 13/15/16, unchanged.
// =====================================================================
__global__ __launch_bounds__(512, 1) void k_mgru(
    const short* __restrict__ gi, const float* __restrict__ mWhh,
    const float* __restrict__ mbhh, float* __restrict__ last)
{
  const int run = blockIdx.x >> 5, grp = blockIdx.x & 31;
  const int g = (run % 4 == 0) ? (run / 4) : (run % 4 + 1);
  const int tid = threadIdx.x;
  const int w = tid >> 6;            // wave 0..7
  const int lane = tid & 63;
  const int c = lane & 15, q = lane >> 4;

  __shared__ short hb[2][4][16][40];
  for (int idx = tid; idx < 2*4*16*40; idx += 512)
    ((short*)hb)[idx] = 0;

  const int jh = w*16 + c;           // hidden index 0..127 (wave-sliced)

  bf16x8 bfrag[3][4];
  #pragma unroll
  for (int gate = 0; gate < 3; ++gate) {
    const float* wp = mWhh + ((size_t)g*384 + gate*128 + jh)*128 + q*8;
    #pragma unroll
    for (int kt = 0; kt < 4; ++kt) {
      float4 lo = *(const float4*)(wp + kt*32);
      float4 hi = *(const float4*)(wp + kt*32 + 4);
      bf16x8 t;
      t[0]=(short)f2bf(lo.x); t[1]=(short)f2bf(lo.y); t[2]=(short)f2bf(lo.z); t[3]=(short)f2bf(lo.w);
      t[4]=(short)f2bf(hi.x); t[5]=(short)f2bf(hi.y); t[6]=(short)f2bf(hi.z); t[7]=(short)f2bf(hi.w);
      bfrag[gate][kt] = t;
    }
  }
  float bh_[3];
  #pragma unroll
  for (int gate = 0; gate < 3; ++gate)
    bh_[gate] = mbhh[g*384 + gate*128 + jh];

  float hf[4] = {0.f,0.f,0.f,0.f};
  const short* gib = gi + (((size_t)run*64 + grp*2 + q)*32)*384*4;  // bf16 [m][384][4]
  const bool act = (lane < 32);

  bf16x4 gA[3], gB[3];
  if (act) {
    #pragma unroll
    for (int gate = 0; gate < 3; ++gate)
      gA[gate] = *(const bf16x4*)&gib[(size_t)(0*384 + gate*128 + jh)*4];
  }
  __syncthreads();

  auto dostep = [&](int m, bf16x4 (&gcur)[3], bf16x4 (&gnext)[3]) {
    const int cur = m & 1, nxt = cur ^ 1;
    bf16x8 a[4];
    #pragma unroll
    for (int kt = 0; kt < 4; ++kt)
      a[kt] = *(const bf16x8*)&hb[cur][kt][c][q*8];

    f32x4 acc[3];
    #pragma unroll
    for (int gate = 0; gate < 3; ++gate) {
      f32x4 t = {0.f,0.f,0.f,0.f};
      #pragma unroll
      for (int kt = 0; kt < 4; ++kt)
        t = __builtin_amdgcn_mfma_f32_16x16x32_bf16(a[kt], bfrag[gate][kt], t, 0, 0, 0);
      acc[gate] = t;
    }

    if (act && m < 31) {
      #pragma unroll
      for (int gate = 0; gate < 3; ++gate)
        gnext[gate] = *(const bf16x4*)&gib[(size_t)((m+1)*384 + gate*128 + jh)*4];
    }

    if (act) {
      const int kt = jh >> 5, kk = jh & 31;
      #pragma unroll
      for (int reg = 0; reg < 4; ++reg) {
        int row = q*4 + reg;
        float g0 = bf2f(gcur[0][reg]);
        float g1 = bf2f(gcur[1][reg]);
        float g2 = bf2f(gcur[2][reg]);
        float rr = fsig(acc[0][reg] + bh_[0] + g0);
        float zz = fsig(acc[1][reg] + bh_[1] + g1);
        float nn = ftanh(g2 + rr*(acc[2][reg] + bh_[2]));
        float hnew = (1.f - zz)*nn + zz*hf[reg];
        hf[reg] = hnew;
        hb[nxt][kt][row][kk] = (short)f2bf(hnew);
      }
    }
    __syncthreads();
  };

  #pragma unroll 1
  for (int m2 = 0; m2 < 16; ++m2) {
    dostep(2*m2,     gA, gB);
    dostep(2*m2 + 1, gB, gA);
  }

  if (act) {
    #pragma unroll
    for (int reg = 0; reg < 4; ++reg)
      last[(run*NSEQ + grp*8 + q*4 + reg)*D_ + jh] = hf[reg];
  }
}

// =====================================================================
// visit-level GRU v3 (vgi fused) — verified round 16, unchanged.
// =====================================================================
__global__ __launch_bounds__(768) void k_vgru(
    const float* __restrict__ last, const float* __restrict__ xe,
    const float* __restrict__ wihTv, const float* __restrict__ vbih,
    const float* __restrict__ vWhh, const float* __restrict__ vbhh,
    float* __restrict__ vh)
{
  int run = blockIdx.x >> 4, b = blockIdx.x & 15;
  int tid = threadIdx.x;
  int vidx = (run < 4) ? 0 : (run < 8) ? 1 : (run - 6);

  __shared__ float Xs[16][128];          // 8 KB
  __shared__ float giL[16*384];          // 24 KB
  __shared__ __align__(16) float hsv[128];
  __shared__ float gh[384];

  const float* X = (run < 8) ? (last + ((size_t)run*NSEQ + b*16)*D_)
                             : (xe + ((size_t)(run-8)*NSEQ + b*16)*D_);
  for (int idx = tid; idx < 2048; idx += 768)
    ((float*)Xs)[idx] = X[idx];
  if (tid < 128) hsv[tid] = 0.f;
  __syncthreads();

  // ---- gi precompute into LDS: thread (half, j) does 8 visits ----
  {
    int half = (tid >= 384) ? 1 : 0;
    int j = tid - half*384;
    float accv[8];
    float bias = vbih[vidx*384 + j];
    #pragma unroll
    for (int s = 0; s < 8; ++s) accv[s] = bias;
    const float* W = wihTv + vidx*49152 + j;
    #pragma unroll 4
    for (int k = 0; k < 128; ++k) {
      float wv = W[k*384];
      #pragma unroll
      for (int s = 0; s < 8; ++s) accv[s] += Xs[half*8 + s][k] * wv;
    }
    #pragma unroll
    for (int s = 0; s < 8; ++s)
      giL[(half*8 + s)*384 + j] = accv[s];
  }

  // ---- recurrence weights (pair-split, w[64]/thread, no spill) ----
  int j = tid >> 1, kh = tid & 1;
  float w[64];
  const float4* wrow = (const float4*)(vWhh + (vidx*384 + j)*128 + kh*64);
  #pragma unroll
  for (int k4 = 0; k4 < 16; ++k4) {
    float4 t4 = wrow[k4];
    w[4*k4] = t4.x; w[4*k4+1] = t4.y; w[4*k4+2] = t4.z; w[4*k4+3] = t4.w;
  }
  float bj = vbhh[vidx*384 + j];
  __syncthreads();

  #pragma unroll 1
  for (int v = 0; v < 16; ++v) {
    const float4* h4 = (const float4*)(hsv + kh*64);
    float p0 = 0.f, p1 = 0.f;
    #pragma unroll
    for (int k4 = 0; k4 < 8; ++k4) {
      float4 u0 = h4[k4], u1 = h4[k4+8];
      p0 += w[4*k4   ]*u0.x + w[4*k4+1 ]*u0.y + w[4*k4+2 ]*u0.z + w[4*k4+3 ]*u0.w;
      p1 += w[4*k4+32]*u1.x + w[4*k4+33]*u1.y + w[4*k4+34]*u1.z + w[4*k4+35]*u1.w;
    }
    float part = p0 + p1;
    part += __shfl_xor(part, 1);
    if (kh == 0) gh[j] = bj + ((j < 256) ? giL[v*384 + j] : 0.f) + part;
    __syncthreads();
    if (tid < 128) {
      float r = fsig(gh[tid]);
      float z = fsig(gh[tid+128]);
      float gin = giL[v*384 + 256 + tid];
      float n = ftanh(gin + r*gh[tid+256]);
      hsv[tid] = (1.f - z)*n + z*hsv[tid];
    }
    __syncthreads();
  }
  if (tid < 128) vh[(run*16 + b)*D_ + tid] = hsv[tid];
}

// =====================================================================
// head v4 (pe fused) — verified round 16, unchanged.
// =====================================================================
__global__ __launch_bounds__(256) void k_head(
    const float* __restrict__ vh, const float* __restrict__ Wp,
    const float* __restrict__ bp, float* __restrict__ out)
{
  const int o = blockIdx.x;
  const int tid = threadIdx.x;
  const int b = tid & 15, kc = tid >> 4;
  const int a1[7] = {0,1,2,3,4,8,9};
  const int a2[7] = {-1,5,6,7,-1,-1,-1};
  const float4* wb = (const float4*)(Wp + (size_t)o*896 + kc*56);
  float acc = 0.f;
  #pragma unroll
  for (int i = 0; i < 14; ++i) {
    int cc2 = kc*56 + i*4;
    int s = cc2 >> 7, d0 = cc2 & 127;
    float4 a = *(const float4*)(vh + (a1[s]*16 + b)*D_ + d0);
    int s2 = a2[s];
    if (s2 >= 0) {
      float4 a2v = *(const float4*)(vh + (s2*16 + b)*D_ + d0);
      a.x += a2v.x; a.y += a2v.y; a.z += a2v.z; a.w += a2v.w;
    }
    a.x = fmaxf(a.x, 0.f); a.y = fmaxf(a.y, 0.f);
    a.z = fmaxf(a.z, 0.f); a.w = fmaxf(a.w, 0.f);
    float4 ww = wb[i];
    acc += a.x*ww.x + a.y*ww.y + a.z*ww.z + a.w*ww.w;
  }
  __shared__ float red[16][17];
  red[kc][b] = acc;
  __syncthreads();
  if (tid < 16) {
    float s = 0.f;
    #pragma unroll
    for (int k = 0; k < 16; ++k) s += red[k][tid];
    out[tid*OUT_ + o] = s + bp[o];
  }
}

// =====================================================================
extern "C" void kernel_launch(void* const* d_in, const int* in_sizes, int n_in,
                              void* d_out, int out_size, void* d_ws, size_t ws_size,
                              hipStream_t stream)
{
  (void)in_sizes; (void)n_in; (void)out_size; (void)ws_size;
  const int*   cc   = (const int*)  d_in[0];
  const int*   cp   = (const int*)  d_in[1];
  const int*   cd   = (const int*)  d_in[2];
  const int*   cli  = (const int*)  d_in[3];
  const int*   clv  = (const int*)  d_in[4];
  const int*   cii  = (const int*)  d_in[5];
  const int*   civ  = (const int*)  d_in[6];
  const float* wgt  = (const float*)d_in[7];
  const float* age  = (const float*)d_in[8];
  const float* ec   = (const float*)d_in[9];
  const float* ep   = (const float*)d_in[10];
  const float* ed   = (const float*)d_in[11];
  const float* eli  = (const float*)d_in[12];
  const float* elv  = (const float*)d_in[13];
  const float* eii  = (const float*)d_in[14];
  const float* eiv  = (const float*)d_in[15];
  const float* mWih = (const float*)d_in[16];
  const float* mWhh = (const float*)d_in[17];
  const float* mbih = (const float*)d_in[18];
  const float* mbhh = (const float*)d_in[19];
  const float* vWih = (const float*)d_in[20];
  const float* vWhh = (const float*)d_in[21];
  const float* vbih = (const float*)d_in[22];
  const float* vbhh = (const float*)d_in[23];
  const float* Wself= (const float*)d_in[24];
  const float* Wmsg = (const float*)d_in[25];
  const float* fwW  = (const float*)d_in[26];
  const float* fwB  = (const float*)d_in[27];
  const float* faW  = (const float*)d_in[28];
  const float* faB  = (const float*)d_in[29];
  const float* Wp   = (const float*)d_in[30];
  const float* bp   = (const float*)d_in[31];
  float* out = (float*)d_out;
  float* ws  = (float*)d_ws;

  float* vis   = ws + OFF_VIS;
  short* visb  = (short*)(ws + OFF_VISB);
  short* monb  = (short*)(ws + OFF_MONB);
  short* totb  = (short*)(ws + OFF_TOTB);
  short* w12t  = (short*)(ws + OFF_W12T);
  short* wihb  = (short*)(ws + OFF_WIHB);
  float* wihTv = ws + OFF_WIHTV;
  float* xe    = ws + OFF_XE;
  short* gi    = (short*)(ws + OFF_GI);
  float* last  = ws + OFF_LAST;
  float* vh    = ws + OFF_VH;

  k_prepvis<<<3392, 256, 0, stream>>>(Wself, Wmsg, mWih, vWih, wgt, age,
                                      fwW, fwB, faW, faB,
                                      cc, cp, cd, ec, ep, ed,
                                      w12t, wihb, wihTv, xe, vis, visb);
  k_mon <<<16384, 128, 0, stream>>>(cli, clv, cii, civ, eli, elv, eii, eiv,
                                    vis, monb, totb);
  k_gg  <<<512, 256, 0, stream>>>(monb, totb, visb, w12t, wihb, mbih, gi);
  k_mgru<<<256, 512, 0, stream>>>(gi, mWhh, mbhh, last);
  k_vgru<<<160, 768, 0, stream>>>(last, xe, wihTv, vbih, vWhh, vbhh, vh);
  k_head<<<600, 256, 0, stream>>>(vh, Wp, bp, out);
}